// Round 5
// baseline (153.160 us; speedup 1.0000x reference)
//
#include <hip/hip_runtime.h>
#include <cstdint>
#include <cstddef>

#define NEG_FILL -1000000.0f

typedef float f32x4 __attribute__((ext_vector_type(4)));

__device__ __forceinline__ f32x4 ntload4(const float* p) {
    return __builtin_nontemporal_load((const f32x4*)p);
}

// HALF-ROW per wave (8192 waves), ALL 16 nt loads issued up front:
// 16 KB/wave in flight, monotone vmcnt drain, no refill choreography.
// 16 waves/CU (VGPR<=128 tier) x 16 KB = 256 KB in flight per CU --
// saturating by Little's law at ~900-cycle HBM latency.
// Rank math / cross-half fixup / epilogue: verified R2 logic, unchanged.
__global__ __launch_bounds__(256, 4) void criterion_rows(
    const float* __restrict__ pred_legal,
    const float* __restrict__ pred_quality,
    const float* __restrict__ target_legal,
    const float* __restrict__ target_quality,
    float* __restrict__ partials, int B) {

    const int tid  = threadIdx.x;
    const int lane = tid & 63;
    const int w    = tid >> 6;
    const int r    = w >> 1;             // local row 0/1
    const int h    = w & 1;              // half 0/1 of the row
    const int b    = blockIdx.x * 2 + r;
    const bool active = (b < B);

    __shared__ float lined[2][256];
    __shared__ float matchv[2][256];
    __shared__ int   scnt_t[4], scnt_p[4];
    __shared__ float sbce[4];
    __shared__ int   sent[4][8];         // packed local (ltr<<8)|lpr

    const float* __restrict__ xrow  = pred_legal   + (size_t)b * 4096 + h * 2048;
    const float* __restrict__ trow  = target_legal + (size_t)b * 4096 + h * 2048;
    const float* __restrict__ pqrow = pred_quality   + (size_t)b * 256;
    const float* __restrict__ tqrow = target_quality + (size_t)b * 256;

    // all 8 stages resident: 16 dwordx4 in flight per wave
    f32x4 xb[8], tb[8];
    if (active) {
        #pragma unroll
        for (int s = 0; s < 8; ++s) {
            const int base = s * 256 + lane * 4;
            xb[s] = ntload4(&xrow[base]);
            tb[s] = ntload4(&trow[base]);
        }
    }

    // init lined/match (overlaps with loads in flight)
    ((float*)lined)[tid]        = NEG_FILL;
    ((float*)lined)[tid + 256]  = NEG_FILL;
    ((float*)matchv)[tid]       = 0.0f;
    ((float*)matchv)[tid + 256] = 0.0f;

    float bce = 0.0f;
    int t_run = 0, p_run = 0, nm = 0;

    if (active) {
        #pragma unroll
        for (int s = 0; s < 8; ++s) {
            const f32x4 x4 = xb[s];
            const f32x4 t4 = tb[s];

            const float xv[4] = {x4.x, x4.y, x4.z, x4.w};
            const float tv[4] = {t4.x, t4.y, t4.z, t4.w};
            uint64_t bt[4], bp[4];
            #pragma unroll
            for (int e = 0; e < 4; ++e) {
                const float x = xv[e], t = tv[e];
                const float a  = __builtin_fabsf(x);
                const float p2 = __builtin_amdgcn_exp2f(a * -1.44269504f);
                const float L  = __builtin_amdgcn_logf(1.0f + p2) * 0.69314718f;
                bce += (0.25f + 0.75f * t) * (fmaxf(x, 0.0f) - x * t + L);
                bt[e] = __ballot(t == 1.0f);
                bp[e] = __ballot(x > 0.0f);
            }

            const uint64_t bm0 = bt[0] & bp[0], bm1 = bt[1] & bp[1];
            const uint64_t bm2 = bt[2] & bp[2], bm3 = bt[3] & bp[3];
            if ((bm0 | bm1 | bm2 | bm3) != 0ull) {   // wave-uniform, rare
                const uint64_t bms[4] = {bm0, bm1, bm2, bm3};
                #pragma unroll
                for (int e = 0; e < 4; ++e) {
                    uint64_t m = bms[e];
                    while (m) {                      // uniform match loop
                        const int j = (int)__builtin_ctzll(m);
                        m &= m - 1;
                        const uint64_t below =
                            (j == 0) ? 0ull : ((~0ull) >> (64 - j));
                        int ltr = t_run, lpr = p_run;   // LOCAL ranks
                        #pragma unroll
                        for (int e2 = 0; e2 < 4; ++e2) {
                            ltr += (int)__popcll(bt[e2] & below);
                            lpr += (int)__popcll(bp[e2] & below);
                            if (e2 < e) {
                                ltr += (int)((bt[e2] >> j) & 1ull);
                                lpr += (int)((bp[e2] >> j) & 1ull);
                            }
                        }
                        // local filter is safe: global rank >= local rank
                        if (ltr < 256 && lpr < 255 && nm < 8) {
                            if (lane == 0) sent[w][nm] = (ltr << 8) | lpr;
                            ++nm;                    // wave-uniform
                        }
                    }
                }
            }
            t_run += (int)(__popcll(bt[0]) + __popcll(bt[1])
                         + __popcll(bt[2]) + __popcll(bt[3]));
            p_run += (int)(__popcll(bp[0]) + __popcll(bp[1])
                         + __popcll(bp[2]) + __popcll(bp[3]));
        }
    }

    #pragma unroll
    for (int off = 32; off > 0; off >>= 1)
        bce += __shfl_xor(bce, off, 64);
    if (lane == 0) {
        scnt_t[w] = t_run; scnt_p[w] = p_run; sbce[w] = bce;
    }
    __syncthreads();

    // ---- globalize ranks (half-1 adds half-0 totals), scatter rare matches ----
    if (active) {
        const int baseT = h ? scnt_t[w - 1] : 0;
        const int baseP = h ? scnt_p[w - 1] : 0;
        for (int i = 0; i < nm; ++i) {               // uniform, rare
            const int ent = sent[w][i];
            const int tr = baseT + (ent >> 8);
            const int pr = baseP + (ent & 0xFF);
            if (tr < 256 && pr < 255 && lane == 0) {
                lined[r][tr]  = pqrow[pr];           // t-ranks unique per row
                matchv[r][tr] = 1.0f;
            }
        }
    }
    __syncthreads();

    // ---- epilogue: one wave per row, CE over [0,255) + MSE on class 255 ----
    if (active && h == 0) {
        float vs[4], tq[4];
        #pragma unroll
        for (int k = 0; k < 4; ++k) {
            const int c = k * 64 + lane;
            vs[k] = lined[r][c];
            tq[k] = tqrow[c] * matchv[r][c];
        }
        if (lane == 63) { vs[3] = -3.0e38f; tq[3] = 0.0f; }  // class 255

        float mx = fmaxf(fmaxf(vs[0], vs[1]), fmaxf(vs[2], vs[3]));
        #pragma unroll
        for (int off = 32; off > 0; off >>= 1)
            mx = fmaxf(mx, __shfl_xor(mx, off, 64));

        float s1 = 0.0f, s2 = 0.0f, s3 = 0.0f;
        #pragma unroll
        for (int k = 0; k < 4; ++k) {
            s1 += __builtin_amdgcn_exp2f((vs[k] - mx) * 1.44269504f);
            s2 += tq[k];
            s3 += tq[k] * vs[k];
        }
        #pragma unroll
        for (int off = 32; off > 0; off >>= 1) {
            s1 += __shfl_xor(s1, off, 64);
            s2 += __shfl_xor(s2, off, 64);
            s3 += __shfl_xor(s3, off, 64);
        }

        if (lane == 0) {
            const float bce_row = sbce[w] + sbce[w + 1];
            const float lse  = mx + __builtin_amdgcn_logf(s1) * 0.69314718f;
            const float csum = -(s3 - lse * s2) / (s2 + 1e-10f);
            const float d    = pqrow[255] - tqrow[255];
            float4 o;
            o.x = bce_row; o.y = csum; o.z = d * d; o.w = 0.0f;
            *(float4*)(partials + (size_t)b * 4) = o;
        }
    }
}

__global__ __launch_bounds__(256) void finalize_kernel(
    const float* __restrict__ partials, float* __restrict__ out, int B) {
    const int tid = threadIdx.x;
    double s0 = 0.0, s1 = 0.0, s2 = 0.0;
    for (int r = tid; r < B; r += 256) {
        const float4 p = *(const float4*)(partials + (size_t)r * 4);
        s0 += (double)p.x; s1 += (double)p.y; s2 += (double)p.z;
    }
    #pragma unroll
    for (int off = 32; off > 0; off >>= 1) {
        s0 += __shfl_xor(s0, off, 64);
        s1 += __shfl_xor(s1, off, 64);
        s2 += __shfl_xor(s2, off, 64);
    }
    __shared__ double red[3][4];
    const int lane = tid & 63, w = tid >> 6;
    if (lane == 0) { red[0][w] = s0; red[1][w] = s1; red[2][w] = s2; }
    __syncthreads();
    if (tid == 0) {
        const double bs = red[0][0] + red[0][1] + red[0][2] + red[0][3];
        const double cs = red[1][0] + red[1][1] + red[1][2] + red[1][3];
        const double qs = red[2][0] + red[2][1] + red[2][2] + red[2][3];
        out[0] = (float)(bs / ((double)B * 4096.0));
        out[1] = (float)(200.0 * (cs / 255.0) + qs / (double)B);
    }
}

extern "C" void kernel_launch(void* const* d_in, const int* in_sizes, int n_in,
                              void* d_out, int out_size, void* d_ws, size_t ws_size,
                              hipStream_t stream) {
    const float* pred_legal     = (const float*)d_in[0];
    const float* pred_quality   = (const float*)d_in[1];
    const float* target_legal   = (const float*)d_in[2];
    const float* target_quality = (const float*)d_in[3];

    const int B = in_sizes[0] / 4096;   // 4096

    float* partials = (float*)d_ws;     // B * 4 floats

    criterion_rows<<<(B + 1) / 2, 256, 0, stream>>>(
        pred_legal, pred_quality, target_legal, target_quality, partials, B);
    finalize_kernel<<<1, 256, 0, stream>>>(partials, (float*)d_out, B);
}